// Round 3
// baseline (256.607 us; speedup 1.0000x reference)
//
#include <hip/hip_runtime.h>
#include <hip/hip_bf16.h>
#include <cstdint>
#include <cstddef>

static constexpr int B_ = 2, S_ = 2048, D_ = 1024, H_ = 16, HD_ = 64;

typedef float f32x4 __attribute__((ext_vector_type(4)));
typedef short bf16x8 __attribute__((ext_vector_type(8)));

__device__ __forceinline__ unsigned short f2bf(float f) {
    union { float f; unsigned int u; } v; v.f = f;
    unsigned int r = v.u + 0x7FFFu + ((v.u >> 16) & 1u);   // RNE
    return (unsigned short)(r >> 16);
}

__device__ __forceinline__ unsigned pack2bf(float a, float b) {
#if __has_builtin(__builtin_amdgcn_cvt_pk_bf16_f32)
    auto p = __builtin_amdgcn_cvt_pk_bf16_f32(a, b);
    unsigned u; __builtin_memcpy(&u, &p, 4);
    return u;
#else
    return (unsigned)f2bf(a) | ((unsigned)f2bf(b) << 16);
#endif
}

// ---------------------------------------------------------------------------
// x (fp32, 4M elems) -> bf16. grid 2048 x 256, 8 elems/thread.
// ---------------------------------------------------------------------------
__global__ __launch_bounds__(256)
void cast_x(const float* __restrict__ x, unsigned short* __restrict__ o) {
    size_t i = ((size_t)blockIdx.x * 256 + threadIdx.x) * 8;
    float4 a = *(const float4*)(x + i);
    float4 c = *(const float4*)(x + i + 4);
    uint4 r;
    r.x = pack2bf(a.x, a.y);
    r.y = pack2bf(a.z, a.w);
    r.z = pack2bf(c.x, c.y);
    r.w = pack2bf(c.z, c.w);
    *(uint4*)(o + i) = r;
}

// ---------------------------------------------------------------------------
// mask int32 (0/1) -> u8. 16 elems/thread.
// ---------------------------------------------------------------------------
__global__ __launch_bounds__(256)
void mask_pack(const int* __restrict__ m, unsigned char* __restrict__ o) {
    size_t i = ((size_t)blockIdx.x * 256 + threadIdx.x) * 16;
    uint4 r;
    unsigned w[4];
    #pragma unroll
    for (int g = 0; g < 4; ++g) {
        int4 v = *(const int4*)(m + i + g * 4);
        w[g] = (v.x ? 1u : 0u) | (v.y ? 1u << 8 : 0u) |
               (v.z ? 1u << 16 : 0u) | (v.w ? 1u << 24 : 0u);
    }
    r.x = w[0]; r.y = w[1]; r.z = w[2]; r.w = w[3];
    *(uint4*)(o + i) = r;
}

// ---------------------------------------------------------------------------
// Wt[mat][n][k] = bf16(W[mat][k][n]) — 64x64 LDS tile transpose. grid (16,16,3)
// ---------------------------------------------------------------------------
__global__ __launch_bounds__(256)
void transpose_w(const float* __restrict__ Wq, const float* __restrict__ Wk,
                 const float* __restrict__ Wv, unsigned short* __restrict__ wt) {
    const int mat = blockIdx.z;
    const float* __restrict__ W = (mat == 0) ? Wq : (mat == 1) ? Wk : Wv;
    unsigned short* __restrict__ o = wt + (size_t)mat * D_ * D_;
    const int n0 = blockIdx.x * 64, k0 = blockIdx.y * 64;
    __shared__ unsigned short Ts[64][72];
    const int t = threadIdx.x;
    {
        const int nl = t & 63, kb = t >> 6;
        #pragma unroll
        for (int i = 0; i < 16; ++i) {
            int k = kb + i * 4;
            Ts[nl][k] = f2bf(W[(size_t)(k0 + k) * D_ + n0 + nl]);
        }
    }
    __syncthreads();
    {
        const int kl = t & 63, nb = t >> 6;
        #pragma unroll
        for (int i = 0; i < 16; ++i) {
            int n = nb + i * 4;
            o[(size_t)(n0 + n) * D_ + k0 + kl] = Ts[n][kl];
        }
    }
}

// ---------------------------------------------------------------------------
// QKV GEMM, bf16 MFMA 16x16x32. 128x128 tile, BK=32, 4 waves x (4x4) 16-tiles.
// mat0 (Q): output scaled by 0.125*log2(e) so attention can use exp2 directly.
// mat2 (V): output written TRANSPOSED as vt[b*H+h][d][s] for the PV B-operand.
// ---------------------------------------------------------------------------
__global__ __launch_bounds__(256)
void qkv_gemm(const unsigned short* __restrict__ xb, const unsigned short* __restrict__ wt,
              const float* __restrict__ bq, const float* __restrict__ bk,
              const float* __restrict__ bv,
              unsigned short* __restrict__ qo, unsigned short* __restrict__ ko,
              unsigned short* __restrict__ vto) {
    const int bx = blockIdx.x;            // 0..23: mat*8 + ntile
    const int by = blockIdx.y;            // 0..31: mtile
    const int mat = bx >> 3;
    const int ncol0 = (bx & 7) * 128;
    const float* __restrict__ bias = (mat == 0) ? bq : (mat == 1) ? bk : bv;
    const unsigned short* __restrict__ Wm = wt + (size_t)mat * D_ * D_;

    __shared__ unsigned short As[128][40];   // [m][k]
    __shared__ unsigned short Bs[128][40];   // [n][k]

    const int t = threadIdx.x;
    const int w = t >> 6, lane = t & 63;
    const int l15 = lane & 15, quad = lane >> 4;
    const int mw = (w >> 1) * 64, nw = (w & 1) * 64;
    const int rowBase = by * 128;

    f32x4 acc[4][4] = {};

    for (int kt = 0; kt < D_; kt += 32) {
        __syncthreads();
        #pragma unroll
        for (int i = 0; i < 2; ++i) {
            int c = t + i * 256;                   // 0..511
            int r = c >> 2, q = c & 3;
            *(uint4*)&As[r][q * 8] =
                *(const uint4*)(xb + (size_t)(rowBase + r) * D_ + kt + q * 8);
            *(uint4*)&Bs[r][q * 8] =
                *(const uint4*)(Wm + (size_t)(ncol0 + r) * D_ + kt + q * 8);
        }
        __syncthreads();

        bf16x8 a[4], b[4];
        #pragma unroll
        for (int i = 0; i < 4; ++i)
            a[i] = *(const bf16x8*)&As[mw + i * 16 + l15][quad * 8];
        #pragma unroll
        for (int j = 0; j < 4; ++j)
            b[j] = *(const bf16x8*)&Bs[nw + j * 16 + l15][quad * 8];
        #pragma unroll
        for (int i = 0; i < 4; ++i)
            #pragma unroll
            for (int j = 0; j < 4; ++j)
                acc[i][j] = __builtin_amdgcn_mfma_f32_16x16x32_bf16(a[i], b[j], acc[i][j], 0, 0, 0);
    }

    if (mat < 2) {
        unsigned short* __restrict__ O = (mat == 0) ? qo : ko;
        const float osc = (mat == 0) ? 0.18033688011112443f : 1.0f;  // 0.125*log2(e)
        #pragma unroll
        for (int j = 0; j < 4; ++j) {
            const int col = ncol0 + nw + j * 16 + l15;
            const float bb = bias[col];
            #pragma unroll
            for (int i = 0; i < 4; ++i)
                #pragma unroll
                for (int r = 0; r < 4; ++r) {
                    const int m = rowBase + mw + i * 16 + quad * 4 + r;
                    O[(size_t)m * D_ + col] = f2bf((acc[i][j][r] + bb) * osc);
                }
        }
    } else {
        // V transposed: vto[((b*H+h)*HD+hd)*S + s]
        #pragma unroll
        for (int j = 0; j < 4; ++j) {
            const int col = ncol0 + nw + j * 16 + l15;
            const float bb = bias[col];
            const int hh = col >> 6, hd = col & 63;
            #pragma unroll
            for (int i = 0; i < 4; ++i)
                #pragma unroll
                for (int r = 0; r < 4; ++r) {
                    const int m = rowBase + mw + i * 16 + quad * 4 + r;
                    const int bg = m >> 11, s = m & 2047;
                    vto[(((size_t)bg * H_ + hh) * HD_ + hd) * S_ + s] =
                        f2bf(acc[i][j][r] + bb);
                }
        }
    }
}

// ---------------------------------------------------------------------------
// Flash attention, bf16 MFMA, S^T orientation.
//   S^T = K·Q^T  -> lane holds P^T[key=quad*4+r][qrow=l15]: mask read is one
//   packed-u8 dword / accumulator group, P store is one ds_write_b64.
//   PV: A = P (from Ps[qrow][key], contiguous b128), B = V^T (from Vt[d][key]).
//   Row-sums via ones-MFMA (bit-consistent with the bf16 P numerator).
// Mask quirk preserved: masked score -> 0 -> p = exp2(0) = 1.
// Q pre-scaled by 0.125*log2(e) -> p = exp2(score) directly.
// ---------------------------------------------------------------------------
__global__ __launch_bounds__(256)
void attn_mfma(const unsigned short* __restrict__ qmat,
               const unsigned short* __restrict__ kmat,
               const unsigned short* __restrict__ vtg,
               const unsigned char* __restrict__ msk, float* __restrict__ out) {
    const int h = blockIdx.x, qt = blockIdx.y, b = blockIdx.z;
    const int t = threadIdx.x, w = t >> 6, lane = t & 63;
    const int l15 = lane & 15, quad = lane >> 4;
    const int q0 = qt * 128;

    __shared__ __align__(16) unsigned short Qs[128][72];   // [qrow][d]
    __shared__ __align__(16) unsigned short Ks[64][72];    // [key][d]
    __shared__ __align__(16) unsigned short Vt[64][72];    // [d][key]
    __shared__ __align__(16) unsigned short Ps[128][72];   // [qrow][key]

    const size_t bh = (size_t)b * S_ * D_ + (size_t)h * HD_;
    const unsigned short* __restrict__ qp = qmat + bh;
    const unsigned short* __restrict__ kp = kmat + bh;
    const unsigned short* __restrict__ vp = vtg + ((size_t)b * H_ + h) * HD_ * S_;
    const unsigned char* __restrict__ mb = msk + (size_t)b * S_ * S_;

    // stage Q tile (128 x 64)
    #pragma unroll
    for (int i = 0; i < 2; ++i) {
        int c = t + i * 256;
        int r = c >> 2, cg = (c & 3) * 16;
        *(uint4*)&Qs[r][cg]     = *(const uint4*)(qp + (size_t)(q0 + r) * D_ + cg);
        *(uint4*)&Qs[r][cg + 8] = *(const uint4*)(qp + (size_t)(q0 + r) * D_ + cg + 8);
    }

    f32x4 accO[2][4] = {};
    f32x4 lsA[2] = {};
    bf16x8 ones;
    #pragma unroll
    for (int i = 0; i < 8; ++i) ones[i] = (short)0x3F80;   // bf16 1.0

    const int rstage = t >> 2, cstage = (t & 3) * 16;

    for (int kt = 0; kt < S_; kt += 64) {
        __syncthreads();                     // prior tile's Ks/Vt reads done
        *(uint4*)&Ks[rstage][cstage]     = *(const uint4*)(kp + (size_t)(kt + rstage) * D_ + cstage);
        *(uint4*)&Ks[rstage][cstage + 8] = *(const uint4*)(kp + (size_t)(kt + rstage) * D_ + cstage + 8);
        *(uint4*)&Vt[rstage][cstage]     = *(const uint4*)(vp + (size_t)rstage * S_ + kt + cstage);
        *(uint4*)&Vt[rstage][cstage + 8] = *(const uint4*)(vp + (size_t)rstage * S_ + kt + cstage + 8);
        __syncthreads();

        // S^T = K · Q^T : m = 64 keys (4 tiles), n = wave's 32 qrows (2 tiles)
        f32x4 sc[4][2] = {};
        #pragma unroll
        for (int kst = 0; kst < 2; ++kst) {
            bf16x8 kfr[4], qfr[2];
            #pragma unroll
            for (int mt = 0; mt < 4; ++mt)
                kfr[mt] = *(const bf16x8*)&Ks[mt * 16 + l15][kst * 32 + quad * 8];
            #pragma unroll
            for (int nt = 0; nt < 2; ++nt)
                qfr[nt] = *(const bf16x8*)&Qs[w * 32 + nt * 16 + l15][kst * 32 + quad * 8];
            #pragma unroll
            for (int mt = 0; mt < 4; ++mt)
                #pragma unroll
                for (int nt = 0; nt < 2; ++nt)
                    sc[mt][nt] = __builtin_amdgcn_mfma_f32_16x16x32_bf16(kfr[mt], qfr[nt], sc[mt][nt], 0, 0, 0);
        }

        // mask + exp2 + packed P^T store (4 consecutive keys per b64 write)
        #pragma unroll
        for (int nt = 0; nt < 2; ++nt) {
            const int qr = w * 32 + nt * 16 + l15;
            const unsigned char* __restrict__ mrow = mb + (size_t)(q0 + qr) * S_ + kt;
            #pragma unroll
            for (int mt = 0; mt < 4; ++mt) {
                const unsigned mu = *(const unsigned*)(mrow + mt * 16 + quad * 4);
                float p[4];
                #pragma unroll
                for (int r = 0; r < 4; ++r) {
                    float e = __builtin_amdgcn_exp2f(sc[mt][nt][r]);
                    p[r] = ((mu >> (8 * r)) & 0xFFu) ? 1.0f : e;
                }
                uint2 pk;
                pk.x = pack2bf(p[0], p[1]);
                pk.y = pack2bf(p[2], p[3]);
                *(uint2*)&Ps[qr][mt * 16 + quad * 4] = pk;
            }
        }
        // Ps rows are wave-private (w*32 strip): no barrier needed.

        // O += P · V^T-as-B ; lsum += P · 1
        #pragma unroll
        for (int kst = 0; kst < 2; ++kst) {
            bf16x8 vfr[4];
            #pragma unroll
            for (int dt = 0; dt < 4; ++dt)
                vfr[dt] = *(const bf16x8*)&Vt[dt * 16 + l15][kst * 32 + quad * 8];
            #pragma unroll
            for (int mt = 0; mt < 2; ++mt) {
                bf16x8 pfr = *(const bf16x8*)&Ps[w * 32 + mt * 16 + l15][kst * 32 + quad * 8];
                #pragma unroll
                for (int dt = 0; dt < 4; ++dt)
                    accO[mt][dt] = __builtin_amdgcn_mfma_f32_16x16x32_bf16(pfr, vfr[dt], accO[mt][dt], 0, 0, 0);
                lsA[mt] = __builtin_amdgcn_mfma_f32_16x16x32_bf16(pfr, ones, lsA[mt], 0, 0, 0);
            }
        }
    }

    // normalize + store: lane holds O[qrow=w*32+mt*16+quad*4+r][d=dt*16+l15]
    float* __restrict__ ob = out + ((size_t)b * S_ + q0) * D_ + (size_t)h * HD_;
    #pragma unroll
    for (int mt = 0; mt < 2; ++mt)
        #pragma unroll
        for (int r = 0; r < 4; ++r) {
            const float inv = 1.0f / lsA[mt][r];
            const int qr = w * 32 + mt * 16 + quad * 4 + r;
            #pragma unroll
            for (int dt = 0; dt < 4; ++dt)
                ob[(size_t)qr * D_ + dt * 16 + l15] = accO[mt][dt][r] * inv;
        }
}

extern "C" void kernel_launch(void* const* d_in, const int* in_sizes, int n_in,
                              void* d_out, int out_size, void* d_ws, size_t ws_size,
                              hipStream_t stream) {
    (void)in_sizes; (void)n_in; (void)out_size; (void)ws_size;
    const float* x    = (const float*)d_in[0];
    const int*   mask = (const int*)d_in[1];
    const float* Wq   = (const float*)d_in[2];
    const float* bq   = (const float*)d_in[3];
    const float* Wk   = (const float*)d_in[4];
    const float* bk   = (const float*)d_in[5];
    const float* Wv   = (const float*)d_in[6];
    const float* bv   = (const float*)d_in[7];
    float* out = (float*)d_out;

    const size_t M1 = (size_t)1024 * 1024;
    unsigned short* xb  = (unsigned short*)d_ws;      // 4M bf16
    unsigned short* wtb = xb + 4 * M1;                // 3M bf16
    unsigned short* qb  = wtb + 3 * M1;               // 4M bf16
    unsigned short* kb  = qb + 4 * M1;                // 4M bf16
    unsigned short* vtb = kb + 4 * M1;                // 4M bf16 (transposed V)
    unsigned char*  mk  = (unsigned char*)(vtb + 4 * M1);  // 8M u8

    cast_x<<<2048, 256, 0, stream>>>(x, xb);
    mask_pack<<<2048, 256, 0, stream>>>(mask, mk);
    transpose_w<<<dim3(16, 16, 3), 256, 0, stream>>>(Wq, Wk, Wv, wtb);
    qkv_gemm<<<dim3(24, 32), 256, 0, stream>>>(xb, wtb, bq, bk, bv, qb, kb, vtb);
    attn_mfma<<<dim3(16, 16, 2), 256, 0, stream>>>(qb, kb, vtb, mk, out);
}

// Round 4
// 252.519 us; speedup vs baseline: 1.0162x; 1.0162x over previous
//
#include <hip/hip_runtime.h>
#include <cstdint>
#include <cstddef>

static constexpr int B_ = 2, S_ = 2048, D_ = 1024, H_ = 16, HD_ = 64;

typedef float f32x4 __attribute__((ext_vector_type(4)));
typedef short bf16x8 __attribute__((ext_vector_type(8)));

__device__ __forceinline__ unsigned short f2bf(float f) {
    union { float f; unsigned int u; } v; v.f = f;
    unsigned int r = v.u + 0x7FFFu + ((v.u >> 16) & 1u);   // RNE
    return (unsigned short)(r >> 16);
}

__device__ __forceinline__ unsigned pack2bf(float a, float b) {
#if __has_builtin(__builtin_amdgcn_cvt_pk_bf16_f32)
    auto p = __builtin_amdgcn_cvt_pk_bf16_f32(a, b);
    unsigned u; __builtin_memcpy(&u, &p, 4);
    return u;
#else
    return (unsigned)f2bf(a) | ((unsigned)f2bf(b) << 16);
#endif
}

// async global->LDS, 16B per lane. LDS dest is wave-uniform base + lane*16.
__device__ __forceinline__ void gload_lds16(const void* g, void* l) {
    __builtin_amdgcn_global_load_lds(
        (const __attribute__((address_space(1))) void*)g,
        (__attribute__((address_space(3))) void*)l, 16, 0, 0);
}

// ---------------------------------------------------------------------------
// x (fp32, 4M elems) -> bf16. grid 2048 x 256, 8 elems/thread.
// ---------------------------------------------------------------------------
__global__ __launch_bounds__(256)
void cast_x(const float* __restrict__ x, unsigned short* __restrict__ o) {
    size_t i = ((size_t)blockIdx.x * 256 + threadIdx.x) * 8;
    float4 a = *(const float4*)(x + i);
    float4 c = *(const float4*)(x + i + 4);
    uint4 r;
    r.x = pack2bf(a.x, a.y);
    r.y = pack2bf(a.z, a.w);
    r.z = pack2bf(c.x, c.y);
    r.w = pack2bf(c.z, c.w);
    *(uint4*)(o + i) = r;
}

// ---------------------------------------------------------------------------
// mask int32 (0/1) -> u8. 16 elems/thread.
// ---------------------------------------------------------------------------
__global__ __launch_bounds__(256)
void mask_pack(const int* __restrict__ m, unsigned char* __restrict__ o) {
    size_t i = ((size_t)blockIdx.x * 256 + threadIdx.x) * 16;
    uint4 r;
    unsigned w[4];
    #pragma unroll
    for (int g = 0; g < 4; ++g) {
        int4 v = *(const int4*)(m + i + g * 4);
        w[g] = (v.x ? 1u : 0u) | (v.y ? 1u << 8 : 0u) |
               (v.z ? 1u << 16 : 0u) | (v.w ? 1u << 24 : 0u);
    }
    r.x = w[0]; r.y = w[1]; r.z = w[2]; r.w = w[3];
    *(uint4*)(o + i) = r;
}

// ---------------------------------------------------------------------------
// Wt[mat][n][k] = bf16(W[mat][k][n]) — 64x64 LDS tile transpose. grid (16,16,3)
// ---------------------------------------------------------------------------
__global__ __launch_bounds__(256)
void transpose_w(const float* __restrict__ Wq, const float* __restrict__ Wk,
                 const float* __restrict__ Wv, unsigned short* __restrict__ wt) {
    const int mat = blockIdx.z;
    const float* __restrict__ W = (mat == 0) ? Wq : (mat == 1) ? Wk : Wv;
    unsigned short* __restrict__ o = wt + (size_t)mat * D_ * D_;
    const int n0 = blockIdx.x * 64, k0 = blockIdx.y * 64;
    __shared__ unsigned short Ts[64][72];
    const int t = threadIdx.x;
    {
        const int nl = t & 63, kb = t >> 6;
        #pragma unroll
        for (int i = 0; i < 16; ++i) {
            int k = kb + i * 4;
            Ts[nl][k] = f2bf(W[(size_t)(k0 + k) * D_ + n0 + nl]);
        }
    }
    __syncthreads();
    {
        const int kl = t & 63, nb = t >> 6;
        #pragma unroll
        for (int i = 0; i < 16; ++i) {
            int n = nb + i * 4;
            o[(size_t)(n0 + n) * D_ + k0 + kl] = Ts[n][kl];
        }
    }
}

// ---------------------------------------------------------------------------
// QKV GEMM, bf16 MFMA 16x16x32, m97-style: unpadded LDS + global_load_lds x4.
// 128x128 tile, BK=32, 4 waves x (4x4) 16-tiles.
// mat0 (Q): output scaled by 0.125*log2(e) so attention can use exp2 directly.
// mat2 (V): output written TRANSPOSED as vt[b*H+h][d][s] for the PV B-operand.
// ---------------------------------------------------------------------------
__global__ __launch_bounds__(256)
void qkv_gemm(const unsigned short* __restrict__ xb, const unsigned short* __restrict__ wt,
              const float* __restrict__ bq, const float* __restrict__ bk,
              const float* __restrict__ bv,
              unsigned short* __restrict__ qo, unsigned short* __restrict__ ko,
              unsigned short* __restrict__ vto) {
    const int bx = blockIdx.x;            // 0..23: mat*8 + ntile
    const int by = blockIdx.y;            // 0..31: mtile
    const int mat = bx >> 3;
    const int ncol0 = (bx & 7) * 128;
    const float* __restrict__ bias = (mat == 0) ? bq : (mat == 1) ? bk : bv;
    const unsigned short* __restrict__ Wm = wt + (size_t)mat * D_ * D_;

    // unpadded, contiguous in lane order for global_load_lds (16B/lane).
    // fragment b128 reads are bank-uniform 8-way (same as m97's layout).
    __shared__ unsigned short As[128 * 32];   // [m][k]
    __shared__ unsigned short Bs[128 * 32];   // [n][k]

    const int t = threadIdx.x;
    const int w = t >> 6, lane = t & 63;
    const int l15 = lane & 15, quad = lane >> 4;
    const int mw = (w >> 1) * 64, nw = (w & 1) * 64;
    const int rowBase = by * 128;

    // this lane's slice of the wave's staging instructions:
    const int srow = lane >> 2;           // 0..15 row within 16-row chunk
    const int scol = (lane & 3) * 8;      // 0/8/16/24 shorts

    f32x4 acc[4][4] = {};

    for (int kt = 0; kt < D_; kt += 32) {
        __syncthreads();                  // prior iter's LDS reads done
        #pragma unroll
        for (int i = 0; i < 2; ++i) {
            const int r0 = w * 32 + i * 16;          // wave-uniform chunk base
            gload_lds16(xb + (size_t)(rowBase + r0 + srow) * D_ + kt + scol,
                        &As[r0 * 32]);
            gload_lds16(Wm + (size_t)(ncol0 + r0 + srow) * D_ + kt + scol,
                        &Bs[r0 * 32]);
        }
        __syncthreads();                  // drains vmcnt -> LDS valid

        bf16x8 a[4], b[4];
        #pragma unroll
        for (int i = 0; i < 4; ++i)
            a[i] = *(const bf16x8*)&As[(mw + i * 16 + l15) * 32 + quad * 8];
        #pragma unroll
        for (int j = 0; j < 4; ++j)
            b[j] = *(const bf16x8*)&Bs[(nw + j * 16 + l15) * 32 + quad * 8];
        #pragma unroll
        for (int i = 0; i < 4; ++i)
            #pragma unroll
            for (int j = 0; j < 4; ++j)
                acc[i][j] = __builtin_amdgcn_mfma_f32_16x16x32_bf16(a[i], b[j], acc[i][j], 0, 0, 0);
    }

    if (mat < 2) {
        unsigned short* __restrict__ O = (mat == 0) ? qo : ko;
        const float osc = (mat == 0) ? 0.18033688011112443f : 1.0f;  // 0.125*log2(e)
        #pragma unroll
        for (int j = 0; j < 4; ++j) {
            const int col = ncol0 + nw + j * 16 + l15;
            const float bb = bias[col];
            #pragma unroll
            for (int i = 0; i < 4; ++i)
                #pragma unroll
                for (int r = 0; r < 4; ++r) {
                    const int m = rowBase + mw + i * 16 + quad * 4 + r;
                    O[(size_t)m * D_ + col] = f2bf((acc[i][j][r] + bb) * osc);
                }
        }
    } else {
        // V transposed: vto[((b*H+h)*HD+hd)*S + s]; 4 consecutive s -> ushort4
        #pragma unroll
        for (int j = 0; j < 4; ++j) {
            const int col = ncol0 + nw + j * 16 + l15;
            const float bb = bias[col];
            const int hh = col >> 6, hd = col & 63;
            #pragma unroll
            for (int i = 0; i < 4; ++i) {
                const int m0 = rowBase + mw + i * 16 + quad * 4;
                const int bg = m0 >> 11, s0 = m0 & 2047;
                ushort4 pk;
                pk.x = f2bf(acc[i][j][0] + bb);
                pk.y = f2bf(acc[i][j][1] + bb);
                pk.z = f2bf(acc[i][j][2] + bb);
                pk.w = f2bf(acc[i][j][3] + bb);
                *(ushort4*)&vto[(((size_t)bg * H_ + hh) * HD_ + hd) * S_ + s0] = pk;
            }
        }
    }
}

// ---------------------------------------------------------------------------
// Flash attention, bf16 MFMA, S^T orientation, Q fragments hoisted to regs.
//   S^T = K·Q^T  -> lane holds P^T[key=quad*4+r][qrow=l15]: packed-u8 mask
//   dword per group, P store is ds_write_b64.
//   PV: A = P (Ps[qrow][key], contiguous b128), B = V^T (Vt[d][key]).
//   Row-sums via ones-MFMA. Masked score -> 0 -> p = exp2(0) = 1 (quirk).
//   Q pre-scaled by 0.125*log2(e) -> p = exp2(score).
// LDS 36 KB -> 4 blocks/CU.
// ---------------------------------------------------------------------------
__global__ __launch_bounds__(256, 4)
void attn_mfma(const unsigned short* __restrict__ qmat,
               const unsigned short* __restrict__ kmat,
               const unsigned short* __restrict__ vtg,
               const unsigned char* __restrict__ msk, float* __restrict__ out) {
    const int h = blockIdx.x, qt = blockIdx.y, b = blockIdx.z;
    const int t = threadIdx.x, w = t >> 6, lane = t & 63;
    const int l15 = lane & 15, quad = lane >> 4;
    const int q0 = qt * 128;

    __shared__ __align__(16) unsigned short Ks[64][72];    // [key][d]
    __shared__ __align__(16) unsigned short Vt[64][72];    // [d][key]
    __shared__ __align__(16) unsigned short Ps[128][72];   // [qrow][key]

    const size_t bh = (size_t)b * S_ * D_ + (size_t)h * HD_;
    const unsigned short* __restrict__ qp = qmat + bh;
    const unsigned short* __restrict__ kp = kmat + bh;
    const unsigned short* __restrict__ vp = vtg + ((size_t)b * H_ + h) * HD_ * S_;
    const unsigned char* __restrict__ mb = msk + (size_t)b * S_ * S_;

    // Q fragments in registers (loop-invariant): B[k=d][n=qrow] layout
    bf16x8 qfr[2][2];
    #pragma unroll
    for (int nt = 0; nt < 2; ++nt)
        #pragma unroll
        for (int kst = 0; kst < 2; ++kst)
            qfr[nt][kst] = *(const bf16x8*)(qp +
                (size_t)(q0 + w * 32 + nt * 16 + l15) * D_ + kst * 32 + quad * 8);

    f32x4 accO[2][4] = {};
    f32x4 lsA[2] = {};
    bf16x8 ones;
    #pragma unroll
    for (int i = 0; i < 8; ++i) ones[i] = (short)0x3F80;   // bf16 1.0

    const int rstage = t >> 2, cstage = (t & 3) * 16;

    for (int kt = 0; kt < S_; kt += 64) {
        __syncthreads();                     // prior tile's Ks/Vt reads done
        *(uint4*)&Ks[rstage][cstage]     = *(const uint4*)(kp + (size_t)(kt + rstage) * D_ + cstage);
        *(uint4*)&Ks[rstage][cstage + 8] = *(const uint4*)(kp + (size_t)(kt + rstage) * D_ + cstage + 8);
        *(uint4*)&Vt[rstage][cstage]     = *(const uint4*)(vp + (size_t)rstage * S_ + kt + cstage);
        *(uint4*)&Vt[rstage][cstage + 8] = *(const uint4*)(vp + (size_t)rstage * S_ + kt + cstage + 8);
        __syncthreads();

        // S^T = K · Q^T : m = 64 keys (4 tiles), n = wave's 32 qrows (2 tiles)
        f32x4 sc[4][2] = {};
        #pragma unroll
        for (int kst = 0; kst < 2; ++kst) {
            bf16x8 kfr[4];
            #pragma unroll
            for (int mt = 0; mt < 4; ++mt)
                kfr[mt] = *(const bf16x8*)&Ks[mt * 16 + l15][kst * 32 + quad * 8];
            #pragma unroll
            for (int mt = 0; mt < 4; ++mt)
                #pragma unroll
                for (int nt = 0; nt < 2; ++nt)
                    sc[mt][nt] = __builtin_amdgcn_mfma_f32_16x16x32_bf16(kfr[mt], qfr[nt][kst], sc[mt][nt], 0, 0, 0);
        }

        // mask + exp2 + packed P^T store (4 consecutive keys per b64 write)
        #pragma unroll
        for (int nt = 0; nt < 2; ++nt) {
            const int qr = w * 32 + nt * 16 + l15;
            const unsigned char* __restrict__ mrow = mb + (size_t)(q0 + qr) * S_ + kt;
            #pragma unroll
            for (int mt = 0; mt < 4; ++mt) {
                const unsigned mu = *(const unsigned*)(mrow + mt * 16 + quad * 4);
                float p[4];
                #pragma unroll
                for (int r = 0; r < 4; ++r) {
                    float e = __builtin_amdgcn_exp2f(sc[mt][nt][r]);
                    p[r] = ((mu >> (8 * r)) & 0xFFu) ? 1.0f : e;
                }
                uint2 pk;
                pk.x = pack2bf(p[0], p[1]);
                pk.y = pack2bf(p[2], p[3]);
                *(uint2*)&Ps[qr][mt * 16 + quad * 4] = pk;
            }
        }
        // Ps rows are wave-private (w*32 strip): no barrier needed.

        // O += P · V^T-as-B ; lsum += P · 1
        #pragma unroll
        for (int kst = 0; kst < 2; ++kst) {
            bf16x8 vfr[4];
            #pragma unroll
            for (int dt = 0; dt < 4; ++dt)
                vfr[dt] = *(const bf16x8*)&Vt[dt * 16 + l15][kst * 32 + quad * 8];
            #pragma unroll
            for (int mt = 0; mt < 2; ++mt) {
                bf16x8 pfr = *(const bf16x8*)&Ps[w * 32 + mt * 16 + l15][kst * 32 + quad * 8];
                #pragma unroll
                for (int dt = 0; dt < 4; ++dt)
                    accO[mt][dt] = __builtin_amdgcn_mfma_f32_16x16x32_bf16(pfr, vfr[dt], accO[mt][dt], 0, 0, 0);
                lsA[mt] = __builtin_amdgcn_mfma_f32_16x16x32_bf16(pfr, ones, lsA[mt], 0, 0, 0);
            }
        }
    }

    // normalize + store: lane holds O[qrow=w*32+mt*16+quad*4+r][d=dt*16+l15]
    float* __restrict__ ob = out + ((size_t)b * S_ + q0) * D_ + (size_t)h * HD_;
    #pragma unroll
    for (int mt = 0; mt < 2; ++mt)
        #pragma unroll
        for (int r = 0; r < 4; ++r) {
            const float inv = 1.0f / lsA[mt][r];
            const int qr = w * 32 + mt * 16 + quad * 4 + r;
            #pragma unroll
            for (int dt = 0; dt < 4; ++dt)
                ob[(size_t)qr * D_ + dt * 16 + l15] = accO[mt][dt][r] * inv;
        }
}

extern "C" void kernel_launch(void* const* d_in, const int* in_sizes, int n_in,
                              void* d_out, int out_size, void* d_ws, size_t ws_size,
                              hipStream_t stream) {
    (void)in_sizes; (void)n_in; (void)out_size; (void)ws_size;
    const float* x    = (const float*)d_in[0];
    const int*   mask = (const int*)d_in[1];
    const float* Wq   = (const float*)d_in[2];
    const float* bq   = (const float*)d_in[3];
    const float* Wk   = (const float*)d_in[4];
    const float* bk   = (const float*)d_in[5];
    const float* Wv   = (const float*)d_in[6];
    const float* bv   = (const float*)d_in[7];
    float* out = (float*)d_out;

    const size_t M1 = (size_t)1024 * 1024;
    unsigned short* xb  = (unsigned short*)d_ws;      // 4M bf16
    unsigned short* wtb = xb + 4 * M1;                // 3M bf16
    unsigned short* qb  = wtb + 3 * M1;               // 4M bf16
    unsigned short* kb  = qb + 4 * M1;                // 4M bf16
    unsigned short* vtb = kb + 4 * M1;                // 4M bf16 (transposed V)
    unsigned char*  mk  = (unsigned char*)(vtb + 4 * M1);  // 8M u8

    cast_x<<<2048, 256, 0, stream>>>(x, xb);
    mask_pack<<<2048, 256, 0, stream>>>(mask, mk);
    transpose_w<<<dim3(16, 16, 3), 256, 0, stream>>>(Wq, Wk, Wv, wtb);
    qkv_gemm<<<dim3(24, 32), 256, 0, stream>>>(xb, wtb, bq, bk, bv, qb, kb, vtb);
    attn_mfma<<<dim3(16, 16, 2), 256, 0, stream>>>(qb, kb, vtb, mk, out);
}

// Round 5
// 234.677 us; speedup vs baseline: 1.0934x; 1.0760x over previous
//
#include <hip/hip_runtime.h>
#include <cstdint>
#include <cstddef>

static constexpr int B_ = 2, S_ = 2048, D_ = 1024, H_ = 16, HD_ = 64;

typedef float f32x4 __attribute__((ext_vector_type(4)));
typedef short bf16x8 __attribute__((ext_vector_type(8)));

__device__ __forceinline__ unsigned short f2bf(float f) {
    union { float f; unsigned int u; } v; v.f = f;
    unsigned int r = v.u + 0x7FFFu + ((v.u >> 16) & 1u);   // RNE
    return (unsigned short)(r >> 16);
}

__device__ __forceinline__ unsigned pack2bf(float a, float b) {
#if __has_builtin(__builtin_amdgcn_cvt_pk_bf16_f32)
    auto p = __builtin_amdgcn_cvt_pk_bf16_f32(a, b);
    unsigned u; __builtin_memcpy(&u, &p, 4);
    return u;
#else
    return (unsigned)f2bf(a) | ((unsigned)f2bf(b) << 16);
#endif
}

// async global->LDS, 16B per lane. LDS dest = wave-uniform base + lane*16.
__device__ __forceinline__ void gload_lds16(const void* g, void* l) {
    __builtin_amdgcn_global_load_lds(
        (const __attribute__((address_space(1))) void*)g,
        (__attribute__((address_space(3))) void*)l, 16, 0, 0);
}

// ---------------------------------------------------------------------------
// Fused prep: [0,2048) cast x->bf16 | [2048,4096) mask int32->u8 |
// [4096,4864) W transpose+cast. One launch; blocks overlap on bandwidth.
// ---------------------------------------------------------------------------
__global__ __launch_bounds__(256)
void prep(const float* __restrict__ x, unsigned short* __restrict__ xo,
          const int* __restrict__ m, unsigned char* __restrict__ mo,
          const float* __restrict__ Wq, const float* __restrict__ Wk,
          const float* __restrict__ Wv, unsigned short* __restrict__ wt) {
    __shared__ unsigned short Ts[64][72];
    const int bid = blockIdx.x, t = threadIdx.x;
    if (bid < 2048) {
        size_t i = ((size_t)bid * 256 + t) * 8;
        float4 a = *(const float4*)(x + i);
        float4 c = *(const float4*)(x + i + 4);
        uint4 r;
        r.x = pack2bf(a.x, a.y); r.y = pack2bf(a.z, a.w);
        r.z = pack2bf(c.x, c.y); r.w = pack2bf(c.z, c.w);
        *(uint4*)(xo + i) = r;
    } else if (bid < 4096) {
        size_t i = ((size_t)(bid - 2048) * 256 + t) * 16;
        uint4 r;
        unsigned w[4];
        #pragma unroll
        for (int g = 0; g < 4; ++g) {
            int4 v = *(const int4*)(m + i + g * 4);
            w[g] = (v.x ? 1u : 0u) | (v.y ? 1u << 8 : 0u) |
                   (v.z ? 1u << 16 : 0u) | (v.w ? 1u << 24 : 0u);
        }
        r.x = w[0]; r.y = w[1]; r.z = w[2]; r.w = w[3];
        *(uint4*)(mo + i) = r;
    } else {
        const int tid = bid - 4096;            // 0..767
        const int mat = tid >> 8, tile = tid & 255;
        const float* __restrict__ W = (mat == 0) ? Wq : (mat == 1) ? Wk : Wv;
        unsigned short* __restrict__ o = wt + (size_t)mat * D_ * D_;
        const int n0 = (tile & 15) * 64, k0 = (tile >> 4) * 64;
        {
            const int nl = t & 63, kb = t >> 6;
            #pragma unroll
            for (int i = 0; i < 16; ++i) {
                int k = kb + i * 4;
                Ts[nl][k] = f2bf(W[(size_t)(k0 + k) * D_ + n0 + nl]);
            }
        }
        __syncthreads();
        {
            const int kl = t & 63, nb = t >> 6;
            #pragma unroll
            for (int i = 0; i < 16; ++i) {
                int n = nb + i * 4;
                o[(size_t)(n0 + n) * D_ + k0 + kl] = Ts[n][kl];
            }
        }
    }
}

// ---------------------------------------------------------------------------
// QKV GEMM, bf16 MFMA 16x16x32. 128x128 tile, BK=32.
// Single-barrier double-buffered DMA K-loop + XOR-swizzled LDS:
//   LDS granule slot p of row R holds global granule p ^ ((R>>1)&3)
//   -> staging lane i (r16=i>>2, slot=i&3) loads global granule slot^((r16>>1)&3)
//   -> fragment read slot = quad ^ ((l15>>1)&3)   (2-way max = free)
// mat0 (Q): scaled by 0.125*log2(e). mat2 (V): stored transposed vt[bh][d][s].
// ---------------------------------------------------------------------------
__global__ __launch_bounds__(256)
void qkv_gemm(const unsigned short* __restrict__ xb, const unsigned short* __restrict__ wt,
              const float* __restrict__ bq, const float* __restrict__ bk,
              const float* __restrict__ bv,
              unsigned short* __restrict__ qo, unsigned short* __restrict__ ko,
              unsigned short* __restrict__ vto) {
    const int bx = blockIdx.x;            // 0..23: mat*8 + ntile
    const int by = blockIdx.y;            // 0..31: mtile
    const int mat = bx >> 3;
    const int ncol0 = (bx & 7) * 128;
    const float* __restrict__ bias = (mat == 0) ? bq : (mat == 1) ? bk : bv;
    const unsigned short* __restrict__ Wm = wt + (size_t)mat * D_ * D_;

    __shared__ unsigned short As[2][128 * 32];
    __shared__ unsigned short Bs[2][128 * 32];

    const int t = threadIdx.x;
    const int w = t >> 6, lane = t & 63;
    const int l15 = lane & 15, quad = lane >> 4;
    const int mw = (w >> 1) * 64, nw = (w & 1) * 64;
    const int rowBase = by * 128;

    const int r16 = lane >> 2;                       // 0..15
    const int sslot = lane & 3;
    const int sg = (sslot ^ ((r16 >> 1) & 3)) * 8;   // staged global col (shorts)
    const int rcol = (quad ^ ((l15 >> 1) & 3)) * 8;  // fragment read col (shorts)

    f32x4 acc[4][4] = {};

    // prologue: stage kt=0 into buffer 0
    #pragma unroll
    for (int j = 0; j < 2; ++j) {
        const int r0 = w * 32 + j * 16;
        gload_lds16(xb + (size_t)(rowBase + r0 + r16) * D_ + sg, &As[0][r0 * 32]);
        gload_lds16(Wm + (size_t)(ncol0 + r0 + r16) * D_ + sg, &Bs[0][r0 * 32]);
    }

    for (int it = 0; it < 32; ++it) {
        const int cur = it & 1;
        __syncthreads();   // drains own DMA (buf cur ready); all readers of buf cur^1 done
        if (it + 1 < 32) {
            const int ktn = (it + 1) * 32;
            #pragma unroll
            for (int j = 0; j < 2; ++j) {
                const int r0 = w * 32 + j * 16;
                gload_lds16(xb + (size_t)(rowBase + r0 + r16) * D_ + ktn + sg,
                            &As[cur ^ 1][r0 * 32]);
                gload_lds16(Wm + (size_t)(ncol0 + r0 + r16) * D_ + ktn + sg,
                            &Bs[cur ^ 1][r0 * 32]);
            }
        }

        bf16x8 a[4], b[4];
        #pragma unroll
        for (int i = 0; i < 4; ++i)
            a[i] = *(const bf16x8*)&As[cur][(mw + i * 16 + l15) * 32 + rcol];
        #pragma unroll
        for (int j = 0; j < 4; ++j)
            b[j] = *(const bf16x8*)&Bs[cur][(nw + j * 16 + l15) * 32 + rcol];
        #pragma unroll
        for (int i = 0; i < 4; ++i)
            #pragma unroll
            for (int j = 0; j < 4; ++j)
                acc[i][j] = __builtin_amdgcn_mfma_f32_16x16x32_bf16(a[i], b[j], acc[i][j], 0, 0, 0);
    }

    if (mat < 2) {
        unsigned short* __restrict__ O = (mat == 0) ? qo : ko;
        const float osc = (mat == 0) ? 0.18033688011112443f : 1.0f;  // 0.125*log2(e)
        #pragma unroll
        for (int j = 0; j < 4; ++j) {
            const int col = ncol0 + nw + j * 16 + l15;
            const float bb = bias[col];
            #pragma unroll
            for (int i = 0; i < 4; ++i)
                #pragma unroll
                for (int r = 0; r < 4; ++r) {
                    const int m = rowBase + mw + i * 16 + quad * 4 + r;
                    O[(size_t)m * D_ + col] = f2bf((acc[i][j][r] + bb) * osc);
                }
        }
    } else {
        #pragma unroll
        for (int j = 0; j < 4; ++j) {
            const int col = ncol0 + nw + j * 16 + l15;
            const float bb = bias[col];
            const int hh = col >> 6, hd = col & 63;
            #pragma unroll
            for (int i = 0; i < 4; ++i) {
                const int m0 = rowBase + mw + i * 16 + quad * 4;
                const int bg = m0 >> 11, s0 = m0 & 2047;
                ushort4 pk;
                pk.x = f2bf(acc[i][j][0] + bb);
                pk.y = f2bf(acc[i][j][1] + bb);
                pk.z = f2bf(acc[i][j][2] + bb);
                pk.w = f2bf(acc[i][j][3] + bb);
                *(ushort4*)&vto[(((size_t)bg * H_ + hh) * HD_ + hd) * S_ + s0] = pk;
            }
        }
    }
}

// ---------------------------------------------------------------------------
// Flash attention, bf16 MFMA, S^T orientation, Q in registers.
// Single-barrier double-buffered DMA K/V staging, XOR-swizzled:
//   row R (64 shorts = 8 granules): slot p holds global granule p ^ (R&7)
//   -> staging lane i (r=i>>3, slot=i&7) loads global granule slot^r
//   -> fragment read slot = (kst*4+quad) ^ (l15&7)   (2-way max = free)
// Mask loads issued BEFORE prefetch DMA so their vmcnt wait doesn't drain it.
// Masked score -> 0 -> p = exp2(0) = 1 (reference quirk). Q pre-scaled.
// ---------------------------------------------------------------------------
__global__ __launch_bounds__(256)
void attn_mfma(const unsigned short* __restrict__ qmat,
               const unsigned short* __restrict__ kmat,
               const unsigned short* __restrict__ vtg,
               const unsigned char* __restrict__ msk, float* __restrict__ out) {
    const int h = blockIdx.x, qt = blockIdx.y, b = blockIdx.z;
    const int t = threadIdx.x, w = t >> 6, lane = t & 63;
    const int l15 = lane & 15, quad = lane >> 4;
    const int q0 = qt * 128;

    __shared__ unsigned short Ks[2][64 * 64];              // [key][d] swizzled
    __shared__ unsigned short Vs[2][64 * 64];              // [d][key] swizzled
    __shared__ __align__(16) unsigned short Ps[128][72];   // [qrow][key] padded

    const size_t bh = (size_t)b * S_ * D_ + (size_t)h * HD_;
    const unsigned short* __restrict__ qp = qmat + bh;
    const unsigned short* __restrict__ kp = kmat + bh;
    const unsigned short* __restrict__ vp = vtg + ((size_t)b * H_ + h) * HD_ * S_;
    const unsigned char* __restrict__ mb = msk + (size_t)b * S_ * S_;

    const int rs = lane >> 3, sslot = lane & 7;
    const int sg = (sslot ^ rs) * 8;         // staged global granule col (shorts)

    // Q fragments in registers (loop-invariant)
    bf16x8 qfr[2][2];
    #pragma unroll
    for (int nt = 0; nt < 2; ++nt)
        #pragma unroll
        for (int kst = 0; kst < 2; ++kst)
            qfr[nt][kst] = *(const bf16x8*)(qp +
                (size_t)(q0 + w * 32 + nt * 16 + l15) * D_ + kst * 32 + quad * 8);

    f32x4 accO[2][4] = {};
    f32x4 lsA[2] = {};
    bf16x8 ones;
    #pragma unroll
    for (int i = 0; i < 8; ++i) ones[i] = (short)0x3F80;   // bf16 1.0

    // prologue: stage tile 0 into buffer 0
    #pragma unroll
    for (int j = 0; j < 2; ++j) {
        const int rb = w * 16 + j * 8;
        gload_lds16(kp + (size_t)(rb + rs) * D_ + sg, &Ks[0][rb * 64]);
        gload_lds16(vp + (size_t)(rb + rs) * S_ + sg, &Vs[0][rb * 64]);
    }

    for (int it = 0; it < 32; ++it) {
        const int cur = it & 1;
        const int kt = it * 64;
        __syncthreads();   // buf cur DMA drained; readers of buf cur^1 done

        // 1) mask loads first (vmcnt FIFO: waiting on these won't drain DMA)
        unsigned mu[2][4];
        #pragma unroll
        for (int nt = 0; nt < 2; ++nt) {
            const int qr = w * 32 + nt * 16 + l15;
            const unsigned char* __restrict__ mrow = mb + (size_t)(q0 + qr) * S_ + kt;
            #pragma unroll
            for (int mt = 0; mt < 4; ++mt)
                mu[nt][mt] = *(const unsigned*)(mrow + mt * 16 + quad * 4);
        }

        // 2) prefetch next tile into the other buffer
        if (it + 1 < 32) {
            const int ktn = kt + 64;
            #pragma unroll
            for (int j = 0; j < 2; ++j) {
                const int rb = w * 16 + j * 8;
                gload_lds16(kp + (size_t)(ktn + rb + rs) * D_ + sg, &Ks[cur ^ 1][rb * 64]);
                gload_lds16(vp + (size_t)(rb + rs) * S_ + ktn + sg, &Vs[cur ^ 1][rb * 64]);
            }
        }

        // 3) S^T = K·Q^T : m = 64 keys (4 tiles), n = wave's 32 qrows (2 tiles)
        f32x4 sc[4][2] = {};
        #pragma unroll
        for (int kst = 0; kst < 2; ++kst) {
            bf16x8 kfr[4];
            #pragma unroll
            for (int mt = 0; mt < 4; ++mt) {
                const int R = mt * 16 + l15;
                kfr[mt] = *(const bf16x8*)&Ks[cur][R * 64 + (((kst * 4 + quad) ^ (l15 & 7)) * 8)];
            }
            #pragma unroll
            for (int mt = 0; mt < 4; ++mt)
                #pragma unroll
                for (int nt = 0; nt < 2; ++nt)
                    sc[mt][nt] = __builtin_amdgcn_mfma_f32_16x16x32_bf16(kfr[mt], qfr[nt][kst], sc[mt][nt], 0, 0, 0);
        }

        // 4) mask + exp2 + packed P^T store (wave-private strip: no barrier)
        #pragma unroll
        for (int nt = 0; nt < 2; ++nt) {
            const int qr = w * 32 + nt * 16 + l15;
            #pragma unroll
            for (int mt = 0; mt < 4; ++mt) {
                float p[4];
                #pragma unroll
                for (int r = 0; r < 4; ++r) {
                    float e = __builtin_amdgcn_exp2f(sc[mt][nt][r]);
                    p[r] = ((mu[nt][mt] >> (8 * r)) & 0xFFu) ? 1.0f : e;
                }
                uint2 pk;
                pk.x = pack2bf(p[0], p[1]);
                pk.y = pack2bf(p[2], p[3]);
                *(uint2*)&Ps[qr][mt * 16 + quad * 4] = pk;
            }
        }

        // 5) O += P·V ; lsum += P·1
        #pragma unroll
        for (int kst = 0; kst < 2; ++kst) {
            bf16x8 vfr[4];
            #pragma unroll
            for (int dt = 0; dt < 4; ++dt) {
                const int R = dt * 16 + l15;
                vfr[dt] = *(const bf16x8*)&Vs[cur][R * 64 + (((kst * 4 + quad) ^ (l15 & 7)) * 8)];
            }
            #pragma unroll
            for (int mt = 0; mt < 2; ++mt) {
                bf16x8 pfr = *(const bf16x8*)&Ps[w * 32 + mt * 16 + l15][kst * 32 + quad * 8];
                #pragma unroll
                for (int dt = 0; dt < 4; ++dt)
                    accO[mt][dt] = __builtin_amdgcn_mfma_f32_16x16x32_bf16(pfr, vfr[dt], accO[mt][dt], 0, 0, 0);
                lsA[mt] = __builtin_amdgcn_mfma_f32_16x16x32_bf16(pfr, ones, lsA[mt], 0, 0, 0);
            }
        }
    }

    // normalize + store
    float* __restrict__ ob = out + ((size_t)b * S_ + q0) * D_ + (size_t)h * HD_;
    #pragma unroll
    for (int mt = 0; mt < 2; ++mt)
        #pragma unroll
        for (int r = 0; r < 4; ++r) {
            const float inv = 1.0f / lsA[mt][r];
            const int qr = w * 32 + mt * 16 + quad * 4 + r;
            #pragma unroll
            for (int dt = 0; dt < 4; ++dt)
                ob[(size_t)qr * D_ + dt * 16 + l15] = accO[mt][dt][r] * inv;
        }
}

extern "C" void kernel_launch(void* const* d_in, const int* in_sizes, int n_in,
                              void* d_out, int out_size, void* d_ws, size_t ws_size,
                              hipStream_t stream) {
    (void)in_sizes; (void)n_in; (void)out_size; (void)ws_size;
    const float* x    = (const float*)d_in[0];
    const int*   mask = (const int*)d_in[1];
    const float* Wq   = (const float*)d_in[2];
    const float* bq   = (const float*)d_in[3];
    const float* Wk   = (const float*)d_in[4];
    const float* bk   = (const float*)d_in[5];
    const float* Wv   = (const float*)d_in[6];
    const float* bv   = (const float*)d_in[7];
    float* out = (float*)d_out;

    const size_t M1 = (size_t)1024 * 1024;
    unsigned short* xb  = (unsigned short*)d_ws;      // 4M bf16
    unsigned short* wtb = xb + 4 * M1;                // 3M bf16
    unsigned short* qb  = wtb + 3 * M1;               // 4M bf16
    unsigned short* kb  = qb + 4 * M1;                // 4M bf16
    unsigned short* vtb = kb + 4 * M1;                // 4M bf16 (transposed V)
    unsigned char*  mk  = (unsigned char*)(vtb + 4 * M1);  // 8M u8

    prep<<<4864, 256, 0, stream>>>(x, xb, mask, mk, Wq, Wk, Wv, wtb);
    qkv_gemm<<<dim3(24, 32), 256, 0, stream>>>(xb, wtb, bq, bk, bv, qb, kb, vtb);
    attn_mfma<<<dim3(16, 16, 2), 256, 0, stream>>>(qb, kb, vtb, mk, out);
}